// Round 7
// baseline (201.785 us; speedup 1.0000x reference)
//
#include <hip/hip_runtime.h>

#define EPSF 1e-10f

constexpr unsigned KEY15 = 0xBFC00000u;  // f2key(1.5f), bucket-aligned
constexpr int BUCK0 = 0xBFC;             // first tracked bucket (3068)
constexpr int NB2   = 4096 - BUCK0;      // 1028 tracked buckets
constexpr int NBKT  = 4096;
constexpr int NREP  = 8;                 // replica rows == NXCD (XCD-aligned!)
constexpr int LHSZ  = NB2 + 64;          // + 64 per-lane dummy slots
constexpr int SGRID = 512;               // 2 blocks/CU; 4 tiles/block at N=2048 tiles

typedef float pf4 __attribute__((ext_vector_type(4)));
typedef int   pi4 __attribute__((ext_vector_type(4)));

// ---------- workspace layout (words) ----------
constexpr int BSTAT_OFF = 64;                       // 4096 float4 (16384 words)
constexpr int REP_OFF   = BSTAT_OFF + 4096 * 4;     // replica-major [NREP][NB2]
constexpr int LOW_OFF   = REP_OFF + NREP * NB2;     // fallback hist (NBKT)
constexpr int ZERO_N    = NREP * NB2;               // only rep needs zeroing

__device__ __forceinline__ float sigmoidf_(float x) {
    return 1.0f / (1.0f + expf(-x));
}
__device__ __forceinline__ float softplusf_(float x) {
    return fmaxf(x, 0.0f) + log1pf(expf(-fabsf(x)));
}
__device__ __forceinline__ unsigned f2key(float x) {
    unsigned b = __float_as_uint(x);
    return b ^ ((unsigned)((int)b >> 31) | 0x80000000u);
}
__device__ __forceinline__ float key2f(unsigned k) {
    unsigned b = (k & 0x80000000u) ? (k & 0x7FFFFFFFu) : ~k;
    return __uint_as_float(b);
}
__device__ __forceinline__ unsigned cload(const unsigned* p) {
    return __hip_atomic_load(p, __ATOMIC_RELAXED, __HIP_MEMORY_SCOPE_AGENT);
}

// ---------------------------------------------------------------------------
__global__ void zeroAll(unsigned* ws) {
    int stride = gridDim.x * 256;
    for (int i = blockIdx.x * 256 + threadIdx.x; i < ZERO_N; i += stride)
        ws[REP_OFF + i] = 0u;
}

// 16-load burst WITHOUT trailing waitcnt (split for cross-tile pipelining).
#define ISSUE16(P, T, pp, pp2, tp, tp2)                                       \
    asm volatile(                                                             \
        "global_load_dwordx4 %0, %16, off\n\t"                                \
        "global_load_dwordx4 %1, %16, off offset:1024\n\t"                    \
        "global_load_dwordx4 %2, %16, off offset:2048\n\t"                    \
        "global_load_dwordx4 %3, %16, off offset:3072\n\t"                    \
        "global_load_dwordx4 %4, %17, off\n\t"                                \
        "global_load_dwordx4 %5, %17, off offset:1024\n\t"                    \
        "global_load_dwordx4 %6, %17, off offset:2048\n\t"                    \
        "global_load_dwordx4 %7, %17, off offset:3072\n\t"                    \
        "global_load_dwordx4 %8, %18, off\n\t"                                \
        "global_load_dwordx4 %9, %18, off offset:1024\n\t"                    \
        "global_load_dwordx4 %10, %18, off offset:2048\n\t"                   \
        "global_load_dwordx4 %11, %18, off offset:3072\n\t"                   \
        "global_load_dwordx4 %12, %19, off\n\t"                               \
        "global_load_dwordx4 %13, %19, off offset:1024\n\t"                   \
        "global_load_dwordx4 %14, %19, off offset:2048\n\t"                   \
        "global_load_dwordx4 %15, %19, off offset:3072"                       \
        : "=&v"(P[0]), "=&v"(P[1]), "=&v"(P[2]), "=&v"(P[3]),                 \
          "=&v"(P[4]), "=&v"(P[5]), "=&v"(P[6]), "=&v"(P[7]),                 \
          "=&v"(T[0]), "=&v"(T[1]), "=&v"(T[2]), "=&v"(T[3]),                 \
          "=&v"(T[4]), "=&v"(T[5]), "=&v"(T[6]), "=&v"(T[7])                  \
        : "v"(pp), "v"(pp2), "v"(tp), "v"(tp2)                                \
        : "memory")

// Counted wait: older burst done, newer (16 loads) still in flight.
// sched_barrier(0) after the bare waitcnt is MANDATORY (rule #18): hipcc
// hoists register-only consumers past inline-asm waitcnt despite "memory".
#define VMWAIT16 do { asm volatile("s_waitcnt vmcnt(16)" ::: "memory");       \
                      __builtin_amdgcn_sched_barrier(0); } while (0)
#define VMWAIT0  do { asm volatile("s_waitcnt vmcnt(0)"  ::: "memory");       \
                      __builtin_amdgcn_sched_barrier(0); } while (0)

#define PROCESS(P, T)                                                         \
    do {                                                                      \
        _Pragma("unroll")                                                     \
        for (int g_ = 0; g_ < 8; g_++) {                                      \
            pf4 pv = P[g_]; pi4 tv = T[g_];                                   \
            _Pragma("unroll")                                                 \
            for (int j_ = 0; j_ < 4; j_++) {                                  \
                float x_ = pv[j_];                                            \
                unsigned key_ = f2key(x_);                                    \
                int bkt_ = (int)(key_ >> 20) - BUCK0;                         \
                bool q_ = (key_ >= KEY15) & (tv[j_] == 0);                    \
                int addr_ = q_ ? bkt_ : dummy;                                \
                atomicAdd(&lh[addr_], 1);                                     \
            }                                                                 \
            if (tv[0] | tv[1] | tv[2] | tv[3]) {                              \
                _Pragma("unroll")                                             \
                for (int j_ = 0; j_ < 4; j_++)                                \
                    if (tv[j_]) {                                             \
                        float x_ = pv[j_];                                    \
                        pc += 1.f; psig += sigmoidf_(x_);                     \
                        plos += softplusf_(x_) - x_;                          \
                    }                                                         \
            }                                                                 \
        }                                                                     \
    } while (0)

// scanK: r0 k1 consume path + XCD-aligned flush, restructured for
// GRID-STRIDE + CROSS-TILE DOUBLE-BUFFER. r0 gave each block ONE tile:
// per block = burst -> full vmcnt(0) stall (~0.9us) -> ~0.3us compute ->
// ~2-3us flush latency => ~5us/block x 8 blocks/CU ~ 46us, stall+flush
// dominated (VALUBusy 17.6%, cached-replay-invariant). Here: 512 blocks
// (2/CU), 4 tiles each; issue tile t+1's burst, counted vmcnt(16) (t done,
// t+1 in flight), process t. Steady-state stall gone; flush amortized 4x.
__global__ __launch_bounds__(256) void scanK(const float* __restrict__ preds,
                                             const int* __restrict__ targs, int N,
                                             float4* __restrict__ bstat,
                                             unsigned* __restrict__ rep) {
    __shared__ int lh[LHSZ];
    for (int i = threadIdx.x; i < LHSZ; i += 256) lh[i] = 0;
    __syncthreads();

    float pc = 0.f, psig = 0.f, plos = 0.f;
    const int tid = threadIdx.x;
    const int lane = tid & 63;
    const int w = tid >> 6;
    const int dummy = NB2 + lane;            // per-lane dummy slot
    const size_t lofs = ((size_t)w << 11) + ((size_t)lane << 2);

    int nfull = N >> 13;                     // full 8192-element tiles
    const int stride = gridDim.x;
    pf4 PA[8], PB[8]; pi4 TA[8], TB[8];

    int g = blockIdx.x;
    if (g < nfull) {
        size_t eb = ((size_t)g << 13) + lofs;
        const float* pp = preds + eb; const float* pp2 = pp + 1024;
        const int*   tp = targs + eb; const int*   tp2 = tp + 1024;
        ISSUE16(PA, TA, pp, pp2, tp, tp2);
    }
    while (g < nfull) {
        int g1 = g + stride;
        if (g1 < nfull) {
            size_t eb = ((size_t)g1 << 13) + lofs;
            const float* pp = preds + eb; const float* pp2 = pp + 1024;
            const int*   tp = targs + eb; const int*   tp2 = tp + 1024;
            ISSUE16(PB, TB, pp, pp2, tp, tp2);
            VMWAIT16;
        } else VMWAIT0;
        PROCESS(PA, TA);                     // tile g
        if (g1 >= nfull) { g = g1; break; }
        int g2 = g1 + stride;
        if (g2 < nfull) {
            size_t eb = ((size_t)g2 << 13) + lofs;
            const float* pp = preds + eb; const float* pp2 = pp + 1024;
            const int*   tp = targs + eb; const int*   tp2 = tp + 1024;
            ISSUE16(PA, TA, pp, pp2, tp, tp2);
            VMWAIT16;
        } else VMWAIT0;
        PROCESS(PB, TB);                     // tile g1
        g = g2;
    }
    // tail elements (N % 8192), last block only
    if (blockIdx.x == gridDim.x - 1) {
        for (int i = (nfull << 13) + tid; i < N; i += 256) {
            float x = preds[i];
            if (targs[i]) { pc += 1.f; psig += sigmoidf_(x); plos += softplusf_(x) - x; }
            else {
                unsigned key = f2key(x);
                if (key >= KEY15) atomicAdd(&lh[(key >> 20) - BUCK0], 1);
            }
        }
    }
    __syncthreads();
    // flush hist once per block (dummy slots >= NB2 ignored) + qualifying count
    float qc = 0.f;
    unsigned* my = rep + (unsigned)(blockIdx.x & (NREP - 1)) * NB2;
    for (int i = tid; i < NB2; i += 256) {
        int c = lh[i];
        if (c) { atomicAdd(&my[i], (unsigned)c); qc += (float)c; }
    }
#pragma unroll
    for (int o = 32; o > 0; o >>= 1) {
        pc   += __shfl_down(pc, o);
        psig += __shfl_down(psig, o);
        plos += __shfl_down(plos, o);
        qc   += __shfl_down(qc, o);
    }
    __shared__ float rp[4], rs[4], rl[4], rq[4];
    if ((tid & 63) == 0) { rp[w] = pc; rs[w] = psig; rl[w] = plos; rq[w] = qc; }
    __syncthreads();
    if (tid == 0)
        bstat[blockIdx.x] = make_float4(rp[0] + rp[1] + rp[2] + rp[3],
                                        rs[0] + rs[1] + rs[2] + rs[3],
                                        rl[0] + rl[1] + rl[2] + rl[3],
                                        rq[0] + rq[1] + rq[2] + rq[3]);
}

// finalizeK: 1 block, merges flagK + redR + lowH + finalize. Real cost ~8us
// warm (the 53us in r6's profile was cold-cache replay artifact: 1-block
// reads of rep/bstat all missing to HBM with limited MLP).
__global__ __launch_bounds__(256) void finalizeK(const float* __restrict__ preds,
                                                 const int* __restrict__ targs, int N,
                                                 int nblocks,
                                                 unsigned* __restrict__ ws,
                                                 float* __restrict__ out) {
    __shared__ unsigned histH[NB2];
    __shared__ unsigned sa[256], sb[256];
    __shared__ int sb1;
    __shared__ unsigned sr1;
    __shared__ float rp[4], rs[4], rl[4], rq[4];
    __shared__ double rds[4], rdl[4];
    __shared__ unsigned s_np, s_k, s_flag;
    __shared__ float s_psig, s_plos;

    const float4*   bstat = (const float4*)(ws + BSTAT_OFF);
    const unsigned* rep   = ws + REP_OFF;
    unsigned*       low   = ws + LOW_OFF;
    const int tid = threadIdx.x;
    const int w = tid >> 6;

    // ---- stage A: reduce per-block stats ----
    {
        float pc = 0.f, ps = 0.f, pl = 0.f, qt = 0.f;
        for (int i = tid; i < nblocks; i += 256) {
            float4 v = bstat[i];
            pc += v.x; ps += v.y; pl += v.z; qt += v.w;
        }
#pragma unroll
        for (int o = 32; o > 0; o >>= 1) {
            pc += __shfl_down(pc, o);
            ps += __shfl_down(ps, o);
            pl += __shfl_down(pl, o);
            qt += __shfl_down(qt, o);
        }
        if ((tid & 63) == 0) { rp[w] = pc; rs[w] = ps; rl[w] = pl; rq[w] = qt; }
        __syncthreads();
        if (tid == 0) {
            unsigned np = (unsigned)(rp[0] + rp[1] + rp[2] + rp[3] + 0.5f);
            float psT = rs[0] + rs[1] + rs[2] + rs[3];
            float plT = rl[0] + rl[1] + rl[2] + rl[3];
            unsigned qtT = (unsigned)(rq[0] + rq[1] + rq[2] + rq[3] + 0.5f);
            unsigned nn = (unsigned)N - np;
            unsigned k = (np == 0u) ? (unsigned)(0.1 * (double)nn)
                                    : ((30u * np < nn) ? 30u * np : nn);
            s_np = np; s_psig = psT; s_plos = plT; s_k = k;
            s_flag = (k > qtT) ? 1u : 0u;
        }
    }

    // ---- stage B: replica reduce (vectorized, replica-major) ----
    for (int t = tid; t * 4 < NB2; t += 256) {
        unsigned a0 = 0, a1 = 0, a2 = 0, a3 = 0;
#pragma unroll
        for (int r = 0; r < NREP; r++) {
            uint4 v = *(const uint4*)(rep + r * NB2 + t * 4);
            a0 += v.x; a1 += v.y; a2 += v.z; a3 += v.w;
        }
        histH[t * 4 + 0] = a0; histH[t * 4 + 1] = a1;
        histH[t * 4 + 2] = a2; histH[t * 4 + 3] = a3;
    }
    __syncthreads();

    // ---- stage C: fallback low-bucket histogram (pathological only) ----
    if (s_flag) {
        for (int i = tid; i < NBKT; i += 256) low[i] = 0u;   // lazy zero
        __syncthreads();
        for (int i = tid; i < N; i += 256) {
            if (!targs[i]) {
                unsigned key = f2key(preds[i]);
                if (key < KEY15) atomicAdd(&low[key >> 20], 1u);
            }
        }
        __syncthreads();
    }

    // ---- stage D: top-k bucket search + analytic sums ----
    {
        int t = tid;
        int base = t * 16;
        unsigned flag = s_flag;
        unsigned c[16]; unsigned tot = 0;
#pragma unroll
        for (int j = 0; j < 16; j++) {
            int b = base + j;
            unsigned s = (b >= BUCK0) ? histH[b - BUCK0] : (flag ? cload(&low[b]) : 0u);
            c[j] = s; tot += s;
        }
        sa[t] = tot;
        if (t == 0) { sb1 = NBKT; sr1 = 0u; }
        __syncthreads();
        unsigned k = s_k;
        unsigned* src = sa; unsigned* dst = sb;
        for (int off = 1; off < 256; off <<= 1) {
            unsigned v = src[t] + ((t + off < 256) ? src[t + off] : 0u);
            dst[t] = v;
            __syncthreads();
            unsigned* tmp = src; src = dst; dst = tmp;
        }
        if (k > 0u) {
            unsigned above = src[t] - tot;
            if (above < k && above + tot >= k) {
                unsigned cum = above;
                for (int j = 15; j >= 0; j--) {
                    unsigned cc = c[j];
                    if (cum + cc >= k) { sb1 = base + j; sr1 = k - cum; break; }
                    cum += cc;
                }
            }
        }
        __syncthreads();
        int b1 = sb1; unsigned r1 = sr1;
        double ssig = 0.0, ssp = 0.0;
#pragma unroll
        for (int j = 0; j < 16; j++) {
            int b = base + j; unsigned cc = c[j];
            if (cc == 0u) continue;
            bool full = (b > b1);
            bool part = (b == b1) && (r1 > 0u);
            if (!(full || part)) continue;
            float lo = key2f((unsigned)b << 20);
            float hi = (b == NBKT - 1) ? key2f(0xFF7FFFFFu)
                                       : key2f(((unsigned)(b + 1)) << 20);
            if (full) {
                float mid = 0.5f * (lo + hi);
                ssig += (double)cc * (double)sigmoidf_(mid);
                ssp  += (double)cc * (double)softplusf_(mid);
            } else {
                unsigned take = (r1 < cc) ? r1 : cc;
                double q = (double)take / (double)cc;
                float rpv = (float)((double)hi - 0.5 * q * ((double)hi - (double)lo));
                ssig += (double)take * (double)sigmoidf_(rpv);
                ssp  += (double)take * (double)softplusf_(rpv);
            }
        }
#pragma unroll
        for (int o = 32; o > 0; o >>= 1) {
            ssig += __shfl_down(ssig, o);
            ssp  += __shfl_down(ssp, o);
        }
        if ((t & 63) == 0) { rds[w] = ssig; rdl[w] = ssp; }
        __syncthreads();
        if (t == 0) {
            double sns = rds[0] + rds[1] + rds[2] + rds[3];
            double snl = rdl[0] + rdl[1] + rdl[2] + rdl[3];
            unsigned np = s_np;
            float psig2 = s_psig, plos2 = s_plos;
            double denom = (double)psig2 + sns + (double)np;
            double dice = 1.0 - (2.0 * (double)psig2 + (double)EPSF) / (denom + (double)EPSF);
            unsigned totsel = np + k;
            double mean = totsel ? (((double)plos2 + snl) / (double)totsel) : 0.0;
            out[0] = (float)(dice + mean);
        }
    }
}

// ---------------------------------------------------------------------------
extern "C" void kernel_launch(void* const* d_in, const int* in_sizes, int n_in,
                              void* d_out, int out_size, void* d_ws, size_t ws_size,
                              hipStream_t stream) {
    const float* preds = (const float*)d_in[0];
    const int*   targs = (const int*)d_in[1];
    float* out = (float*)d_out;
    int N = in_sizes[0];

    unsigned* ws  = (unsigned*)d_ws;
    float4* bstat = (float4*)(ws + BSTAT_OFF);
    unsigned* rep = ws + REP_OFF;

    int nfull = N >> 13;
    int need = nfull + ((N & 8191) ? 1 : 0);
    if (need < 1) need = 1;
    int grid = (need < SGRID) ? need : SGRID;   // blocks grid-stride past

    zeroAll<<<32, 256, 0, stream>>>(ws);
    scanK<<<grid, 256, 0, stream>>>(preds, targs, N, bstat, rep);
    finalizeK<<<1, 256, 0, stream>>>(preds, targs, N, grid, ws, out);
}

// Round 8
// 162.598 us; speedup vs baseline: 1.2410x; 1.2410x over previous
//
#include <hip/hip_runtime.h>

#define EPSF 1e-10f

constexpr unsigned KEY15 = 0xBFC00000u;  // f2key(1.5f), bucket-aligned
constexpr int BUCK0 = 0xBFC;             // first tracked bucket (3068)
constexpr int NB2   = 4096 - BUCK0;      // 1028 tracked buckets
constexpr int NBKT  = 4096;
constexpr int NREP  = 8;                 // replica rows == NXCD (XCD-aligned!)
constexpr int LHSZ  = NB2 + 64;          // + 64 per-lane dummy slots

typedef float pf4 __attribute__((ext_vector_type(4)));
typedef int   pi4 __attribute__((ext_vector_type(4)));

// ---------- workspace layout (words) ----------
constexpr int BSTAT_OFF = 64;                       // 4096 float4 (16384 words)
constexpr int REP_OFF   = BSTAT_OFF + 4096 * 4;     // replica-major [NREP][NB2]
constexpr int LOW_OFF   = REP_OFF + NREP * NB2;     // fallback hist (NBKT)
constexpr int ZERO_N    = NREP * NB2;               // only rep needs zeroing

__device__ __forceinline__ float sigmoidf_(float x) {
    return 1.0f / (1.0f + expf(-x));
}
__device__ __forceinline__ float softplusf_(float x) {
    return fmaxf(x, 0.0f) + log1pf(expf(-fabsf(x)));
}
__device__ __forceinline__ unsigned f2key(float x) {
    unsigned b = __float_as_uint(x);
    return b ^ ((unsigned)((int)b >> 31) | 0x80000000u);
}
__device__ __forceinline__ float key2f(unsigned k) {
    unsigned b = (k & 0x80000000u) ? (k & 0x7FFFFFFFu) : ~k;
    return __uint_as_float(b);
}
__device__ __forceinline__ unsigned cload(const unsigned* p) {
    return __hip_atomic_load(p, __ATOMIC_RELAXED, __HIP_MEMORY_SCOPE_AGENT);
}

// ---------------------------------------------------------------------------
__global__ void zeroAll(unsigned* ws) {
    int stride = gridDim.x * 256;
    for (int i = blockIdx.x * 256 + threadIdx.x; i < ZERO_N; i += stride)
        ws[REP_OFF + i] = 0u;
}

// 8-load single-array burst + vmcnt(0): proven r0 MLP/TLP structure, halved.
#define ISSUE8(V, p0, p1)                                                     \
    asm volatile(                                                             \
        "global_load_dwordx4 %0, %8, off\n\t"                                 \
        "global_load_dwordx4 %1, %8, off offset:1024\n\t"                     \
        "global_load_dwordx4 %2, %8, off offset:2048\n\t"                     \
        "global_load_dwordx4 %3, %8, off offset:3072\n\t"                     \
        "global_load_dwordx4 %4, %9, off\n\t"                                 \
        "global_load_dwordx4 %5, %9, off offset:1024\n\t"                     \
        "global_load_dwordx4 %6, %9, off offset:2048\n\t"                     \
        "global_load_dwordx4 %7, %9, off offset:3072\n\t"                     \
        "s_waitcnt vmcnt(0)"                                                  \
        : "=&v"(V[0]), "=&v"(V[1]), "=&v"(V[2]), "=&v"(V[3]),                 \
          "=&v"(V[4]), "=&v"(V[5]), "=&v"(V[6]), "=&v"(V[7])                  \
        : "v"(p0), "v"(p1)                                                    \
        : "memory")

// scanP: preds-only histogram pass (STREAM SPLIT). Histograms EVERY element
// with key>=1.5 — positives included; scanT subtracts them exactly. Same
// 1-tile-per-block TLP structure as r0 (r7 proved 8 blocks/CU TLP > reg
// double-buffer ILP), but half the loads and no targs coupling in the chain.
__global__ __launch_bounds__(256) void scanP(const float* __restrict__ preds,
                                             int N, unsigned* __restrict__ rep) {
    __shared__ int lh[LHSZ];
    for (int i = threadIdx.x; i < LHSZ; i += 256) lh[i] = 0;
    __syncthreads();

    const int tid = threadIdx.x;
    const int lane = tid & 63;
    const int w = tid >> 6;
    const int dummy = NB2 + lane;            // per-lane dummy slot

    int nfull = N >> 13;                     // full 8192-element tiles
    for (int grp = blockIdx.x; grp < nfull; grp += gridDim.x) {
        size_t ebase = ((size_t)grp << 13) + ((size_t)w << 11) + ((size_t)lane << 2);
        const float* pp  = preds + ebase;    // wave tile: 2048 elements
        const float* pp2 = pp + 1024;
        pf4 P[8];
        ISSUE8(P, pp, pp2);
#pragma unroll
        for (int g = 0; g < 8; g++) {
            pf4 pv = P[g];
#pragma unroll
            for (int j = 0; j < 4; j++) {
                unsigned key = f2key(pv[j]);
                int bkt = (int)(key >> 20) - BUCK0;
                int addr = (key >= KEY15) ? bkt : dummy;  // v_cndmask
                atomicAdd(&lh[addr], 1);                  // unconditional ds_add
            }
        }
    }
    // tail elements (N % 8192), last block only
    if (blockIdx.x == gridDim.x - 1) {
        for (int i = (nfull << 13) + tid; i < N; i += 256) {
            unsigned key = f2key(preds[i]);
            if (key >= KEY15) atomicAdd(&lh[(key >> 20) - BUCK0], 1);
        }
    }
    __syncthreads();
    // flush hist (dummy slots >= NB2 ignored); XCD-aligned replica (bid&7)
    unsigned* my = rep + (unsigned)(blockIdx.x & (NREP - 1)) * NB2;
    for (int i = tid; i < NB2; i += 256) {
        int c = lh[i];
        if (c) atomicAdd(&my[i], (unsigned)c);
    }
}

// scanT: targs-only filter pass. 99.6% of int4 groups are all-zero -> near
// copy-rate stream. For each positive (~16.7K total): scattered preds[i]
// load, accumulate positive stats, and DECREMENT its bucket in rep (exact
// cancellation of scanP's over-count; unsigned wrap across replicas is safe
// since the final sum is the true non-negative count mod 2^32).
__global__ __launch_bounds__(256) void scanT(const float* __restrict__ preds,
                                             const int* __restrict__ targs, int N,
                                             float4* __restrict__ bstat,
                                             unsigned* __restrict__ rep) {
    float pc = 0.f, psig = 0.f, plos = 0.f;
    const int tid = threadIdx.x;
    const int w = tid >> 6;
    const int lane = tid & 63;
    unsigned* my = rep + (unsigned)(blockIdx.x & (NREP - 1)) * NB2;

    int nfull = N >> 13;
    for (int grp = blockIdx.x; grp < nfull; grp += gridDim.x) {
        size_t ebase = ((size_t)grp << 13) + ((size_t)w << 11) + ((size_t)lane << 2);
        const int* tp  = targs + ebase;
        const int* tp2 = tp + 1024;
        pi4 T[8];
        ISSUE8(T, tp, tp2);
#pragma unroll
        for (int g = 0; g < 8; g++) {
            pi4 tv = T[g];
            if (tv[0] | tv[1] | tv[2] | tv[3]) {       // rare positive path
                size_t gofs = ebase + (size_t)(g & 3) * 256 + (size_t)(g >> 2) * 1024;
#pragma unroll
                for (int j = 0; j < 4; j++)
                    if (tv[j]) {
                        float x = preds[gofs + j];
                        pc += 1.f; psig += sigmoidf_(x); plos += softplusf_(x) - x;
                        unsigned key = f2key(x);
                        if (key >= KEY15)
                            atomicAdd(&my[(key >> 20) - BUCK0], 0xFFFFFFFFu);
                    }
            }
        }
    }
    // tail elements (N % 8192), last block only
    if (blockIdx.x == gridDim.x - 1) {
        for (int i = (nfull << 13) + tid; i < N; i += 256) {
            if (targs[i]) {
                float x = preds[i];
                pc += 1.f; psig += sigmoidf_(x); plos += softplusf_(x) - x;
                unsigned key = f2key(x);
                if (key >= KEY15)
                    atomicAdd(&my[(key >> 20) - BUCK0], 0xFFFFFFFFu);
            }
        }
    }
#pragma unroll
    for (int o = 32; o > 0; o >>= 1) {
        pc   += __shfl_down(pc, o);
        psig += __shfl_down(psig, o);
        plos += __shfl_down(plos, o);
    }
    __shared__ float rp[4], rs[4], rl[4];
    if ((tid & 63) == 0) { rp[w] = pc; rs[w] = psig; rl[w] = plos; }
    __syncthreads();
    if (tid == 0)
        bstat[blockIdx.x] = make_float4(rp[0] + rp[1] + rp[2] + rp[3],
                                        rs[0] + rs[1] + rs[2] + rs[3],
                                        rl[0] + rl[1] + rl[2] + rl[3], 0.f);
}

// finalizeK: replica reduce (with scanT's decrements already applied) ->
// qtT = sum(histH) derived here (no in-scan qc needed) -> stats -> top-k.
__global__ __launch_bounds__(256) void finalizeK(const float* __restrict__ preds,
                                                 const int* __restrict__ targs, int N,
                                                 int nblocks,
                                                 unsigned* __restrict__ ws,
                                                 float* __restrict__ out) {
    __shared__ unsigned histH[NB2];
    __shared__ unsigned sa[256], sb[256];
    __shared__ int sb1;
    __shared__ unsigned sr1;
    __shared__ float rp[4], rs[4], rl[4];
    __shared__ float rq[4];
    __shared__ double rds[4], rdl[4];
    __shared__ unsigned s_np, s_k, s_flag;
    __shared__ float s_psig, s_plos;

    const float4*   bstat = (const float4*)(ws + BSTAT_OFF);
    const unsigned* rep   = ws + REP_OFF;
    unsigned*       low   = ws + LOW_OFF;
    const int tid = threadIdx.x;
    const int w = tid >> 6;

    // ---- stage B: replica reduce (vectorized) + qtT partial ----
    float qpart = 0.f;
    for (int t = tid; t * 4 < NB2; t += 256) {
        unsigned a0 = 0, a1 = 0, a2 = 0, a3 = 0;
#pragma unroll
        for (int r = 0; r < NREP; r++) {
            uint4 v = *(const uint4*)(rep + r * NB2 + t * 4);
            a0 += v.x; a1 += v.y; a2 += v.z; a3 += v.w;
        }
        histH[t * 4 + 0] = a0; histH[t * 4 + 1] = a1;
        histH[t * 4 + 2] = a2; histH[t * 4 + 3] = a3;
        qpart += (float)a0 + (float)a1 + (float)a2 + (float)a3;
    }

    // ---- stage A: reduce per-block stats + qtT ----
    {
        float pc = 0.f, ps = 0.f, pl = 0.f;
        for (int i = tid; i < nblocks; i += 256) {
            float4 v = bstat[i];
            pc += v.x; ps += v.y; pl += v.z;
        }
#pragma unroll
        for (int o = 32; o > 0; o >>= 1) {
            pc += __shfl_down(pc, o);
            ps += __shfl_down(ps, o);
            pl += __shfl_down(pl, o);
            qpart += __shfl_down(qpart, o);
        }
        if ((tid & 63) == 0) { rp[w] = pc; rs[w] = ps; rl[w] = pl; rq[w] = qpart; }
        __syncthreads();
        if (tid == 0) {
            unsigned np = (unsigned)(rp[0] + rp[1] + rp[2] + rp[3] + 0.5f);
            float psT = rs[0] + rs[1] + rs[2] + rs[3];
            float plT = rl[0] + rl[1] + rl[2] + rl[3];
            unsigned qtT = (unsigned)(rq[0] + rq[1] + rq[2] + rq[3] + 0.5f);
            unsigned nn = (unsigned)N - np;
            unsigned k = (np == 0u) ? (unsigned)(0.1 * (double)nn)
                                    : ((30u * np < nn) ? 30u * np : nn);
            s_np = np; s_psig = psT; s_plos = plT; s_k = k;
            s_flag = (k > qtT) ? 1u : 0u;
        }
    }
    __syncthreads();

    // ---- stage C: fallback low-bucket histogram (pathological only) ----
    if (s_flag) {
        for (int i = tid; i < NBKT; i += 256) low[i] = 0u;   // lazy zero
        __syncthreads();
        for (int i = tid; i < N; i += 256) {
            if (!targs[i]) {
                unsigned key = f2key(preds[i]);
                if (key < KEY15) atomicAdd(&low[key >> 20], 1u);
            }
        }
        __syncthreads();
    }

    // ---- stage D: top-k bucket search + analytic sums ----
    {
        int t = tid;
        int base = t * 16;
        unsigned flag = s_flag;
        unsigned c[16]; unsigned tot = 0;
#pragma unroll
        for (int j = 0; j < 16; j++) {
            int b = base + j;
            unsigned s = (b >= BUCK0) ? histH[b - BUCK0] : (flag ? cload(&low[b]) : 0u);
            c[j] = s; tot += s;
        }
        sa[t] = tot;
        if (t == 0) { sb1 = NBKT; sr1 = 0u; }
        __syncthreads();
        unsigned k = s_k;
        unsigned* src = sa; unsigned* dst = sb;
        for (int off = 1; off < 256; off <<= 1) {
            unsigned v = src[t] + ((t + off < 256) ? src[t + off] : 0u);
            dst[t] = v;
            __syncthreads();
            unsigned* tmp = src; src = dst; dst = tmp;
        }
        if (k > 0u) {
            unsigned above = src[t] - tot;
            if (above < k && above + tot >= k) {
                unsigned cum = above;
                for (int j = 15; j >= 0; j--) {
                    unsigned cc = c[j];
                    if (cum + cc >= k) { sb1 = base + j; sr1 = k - cum; break; }
                    cum += cc;
                }
            }
        }
        __syncthreads();
        int b1 = sb1; unsigned r1 = sr1;
        double ssig = 0.0, ssp = 0.0;
#pragma unroll
        for (int j = 0; j < 16; j++) {
            int b = base + j; unsigned cc = c[j];
            if (cc == 0u) continue;
            bool full = (b > b1);
            bool part = (b == b1) && (r1 > 0u);
            if (!(full || part)) continue;
            float lo = key2f((unsigned)b << 20);
            float hi = (b == NBKT - 1) ? key2f(0xFF7FFFFFu)
                                       : key2f(((unsigned)(b + 1)) << 20);
            if (full) {
                float mid = 0.5f * (lo + hi);
                ssig += (double)cc * (double)sigmoidf_(mid);
                ssp  += (double)cc * (double)softplusf_(mid);
            } else {
                unsigned take = (r1 < cc) ? r1 : cc;
                double q = (double)take / (double)cc;
                float rpv = (float)((double)hi - 0.5 * q * ((double)hi - (double)lo));
                ssig += (double)take * (double)sigmoidf_(rpv);
                ssp  += (double)take * (double)softplusf_(rpv);
            }
        }
#pragma unroll
        for (int o = 32; o > 0; o >>= 1) {
            ssig += __shfl_down(ssig, o);
            ssp  += __shfl_down(ssp, o);
        }
        if ((t & 63) == 0) { rds[w] = ssig; rdl[w] = ssp; }
        __syncthreads();
        if (t == 0) {
            double sns = rds[0] + rds[1] + rds[2] + rds[3];
            double snl = rdl[0] + rdl[1] + rdl[2] + rdl[3];
            unsigned np = s_np;
            float psig2 = s_psig, plos2 = s_plos;
            double denom = (double)psig2 + sns + (double)np;
            double dice = 1.0 - (2.0 * (double)psig2 + (double)EPSF) / (denom + (double)EPSF);
            unsigned totsel = np + s_k;
            double mean = totsel ? (((double)plos2 + snl) / (double)totsel) : 0.0;
            out[0] = (float)(dice + mean);
        }
    }
}

// ---------------------------------------------------------------------------
extern "C" void kernel_launch(void* const* d_in, const int* in_sizes, int n_in,
                              void* d_out, int out_size, void* d_ws, size_t ws_size,
                              hipStream_t stream) {
    const float* preds = (const float*)d_in[0];
    const int*   targs = (const int*)d_in[1];
    float* out = (float*)d_out;
    int N = in_sizes[0];

    unsigned* ws  = (unsigned*)d_ws;
    float4* bstat = (float4*)(ws + BSTAT_OFF);
    unsigned* rep = ws + REP_OFF;

    int nfull = N >> 13;
    int grid = nfull + ((N & 8191) ? 1 : 0);
    if (grid < 1) grid = 1;
    if (grid > 4096) grid = 4096;   // bstat bound; blocks grid-stride past

    zeroAll<<<32, 256, 0, stream>>>(ws);
    scanP<<<grid, 256, 0, stream>>>(preds, N, rep);
    scanT<<<grid, 256, 0, stream>>>(preds, targs, N, bstat, rep);
    finalizeK<<<1, 256, 0, stream>>>(preds, targs, N, grid, ws, out);
}

// Round 9
// 159.688 us; speedup vs baseline: 1.2636x; 1.0182x over previous
//
#include <hip/hip_runtime.h>

#define EPSF 1e-10f

constexpr unsigned KEY15 = 0xBFC00000u;  // f2key(1.5f), bucket-aligned
constexpr int BUCK0 = 0xBFC;             // first tracked bucket (3068)
constexpr int NB2   = 4096 - BUCK0;      // 1028 tracked buckets
constexpr int NBKT  = 4096;
constexpr int NREP  = 8;                 // replica rows == NXCD (XCD-aligned!)
constexpr int LHSZ  = NB2 + 64;          // + 64 per-lane dummy slots

typedef float pf4 __attribute__((ext_vector_type(4)));
typedef int   pi4 __attribute__((ext_vector_type(4)));

// ---------- workspace layout (words) ----------
constexpr int BSTAT_OFF = 64;                       // 4096 float4 (16384 words)
constexpr int REP_OFF   = BSTAT_OFF + 4096 * 4;     // replica-major [NREP][NB2]
constexpr int LOW_OFF   = REP_OFF + NREP * NB2;     // fallback hist (NBKT)
constexpr int ZERO_N    = NREP * NB2;               // only rep needs zeroing

__device__ __forceinline__ float sigmoidf_(float x) {
    return 1.0f / (1.0f + expf(-x));
}
__device__ __forceinline__ float softplusf_(float x) {
    return fmaxf(x, 0.0f) + log1pf(expf(-fabsf(x)));
}
__device__ __forceinline__ unsigned f2key(float x) {
    unsigned b = __float_as_uint(x);
    return b ^ ((unsigned)((int)b >> 31) | 0x80000000u);
}
__device__ __forceinline__ float key2f(unsigned k) {
    unsigned b = (k & 0x80000000u) ? (k & 0x7FFFFFFFu) : ~k;
    return __uint_as_float(b);
}
__device__ __forceinline__ unsigned cload(const unsigned* p) {
    return __hip_atomic_load(p, __ATOMIC_RELAXED, __HIP_MEMORY_SCOPE_AGENT);
}

// ---------------------------------------------------------------------------
__global__ void zeroAll(unsigned* ws) {
    int stride = gridDim.x * 256;
    for (int i = blockIdx.x * 256 + threadIdx.x; i < ZERO_N; i += stride)
        ws[REP_OFF + i] = 0u;
}

// 16-load burst, PAIR-INTERLEAVED issue order (p_g, t_g adjacent) and NO
// trailing wait. vmcnt retires in issue order, so vmcnt(14-2g) == "group g's
// pred+targ quad has landed" while groups g+1..7 are still in flight.
#define ISSUE16I(P, T, pp, pp2, tp, tp2)                                      \
    asm volatile(                                                             \
        "global_load_dwordx4 %0, %16, off\n\t"                                \
        "global_load_dwordx4 %8, %18, off\n\t"                                \
        "global_load_dwordx4 %1, %16, off offset:1024\n\t"                    \
        "global_load_dwordx4 %9, %18, off offset:1024\n\t"                    \
        "global_load_dwordx4 %2, %16, off offset:2048\n\t"                    \
        "global_load_dwordx4 %10, %18, off offset:2048\n\t"                   \
        "global_load_dwordx4 %3, %16, off offset:3072\n\t"                    \
        "global_load_dwordx4 %11, %18, off offset:3072\n\t"                   \
        "global_load_dwordx4 %4, %17, off\n\t"                                \
        "global_load_dwordx4 %12, %19, off\n\t"                               \
        "global_load_dwordx4 %5, %17, off offset:1024\n\t"                    \
        "global_load_dwordx4 %13, %19, off offset:1024\n\t"                   \
        "global_load_dwordx4 %6, %17, off offset:2048\n\t"                    \
        "global_load_dwordx4 %14, %19, off offset:2048\n\t"                   \
        "global_load_dwordx4 %7, %17, off offset:3072\n\t"                    \
        "global_load_dwordx4 %15, %19, off offset:3072"                       \
        : "=&v"(P[0]), "=&v"(P[1]), "=&v"(P[2]), "=&v"(P[3]),                 \
          "=&v"(P[4]), "=&v"(P[5]), "=&v"(P[6]), "=&v"(P[7]),                 \
          "=&v"(T[0]), "=&v"(T[1]), "=&v"(T[2]), "=&v"(T[3]),                 \
          "=&v"(T[4]), "=&v"(T[5]), "=&v"(T[6]), "=&v"(T[7])                  \
        : "v"(pp), "v"(pp2), "v"(tp), "v"(tp2)                                \
        : "memory")

// Counted wait + scheduler fence (rule #18: sched_barrier(0) stops hipcc
// hoisting register consumers above an inline-asm waitcnt). Pattern
// correctness-proven in r7 (counted vmcnt(16) + sched_barrier passed).
#define WAITG(n) do { asm volatile("s_waitcnt vmcnt(" #n ")" ::: "memory");   \
                      __builtin_amdgcn_sched_barrier(0); } while (0)

// Per-group consume: branchless cndmask->ds_add + rare positive path.
#define DOGRP(gq)                                                             \
    do {                                                                      \
        pf4 pv = P[gq]; pi4 tv = T[gq];                                       \
        _Pragma("unroll")                                                     \
        for (int j_ = 0; j_ < 4; j_++) {                                      \
            float x_ = pv[j_];                                                \
            unsigned key_ = f2key(x_);                                        \
            int bkt_ = (int)(key_ >> 20) - BUCK0;                             \
            bool q_ = (key_ >= KEY15) & (tv[j_] == 0);                        \
            int addr_ = q_ ? bkt_ : dummy;                                    \
            atomicAdd(&lh[addr_], 1);                                         \
        }                                                                     \
        if (tv[0] | tv[1] | tv[2] | tv[3]) {                                  \
            _Pragma("unroll")                                                 \
            for (int j_ = 0; j_ < 4; j_++)                                    \
                if (tv[j_]) {                                                 \
                    float x_ = pv[j_];                                        \
                    pc += 1.f; psig += sigmoidf_(x_);                         \
                    plos += softplusf_(x_) - x_;                              \
                }                                                             \
        }                                                                     \
    } while (0)

// scanK: r6 proven structure (1 tile/block, 8 blocks/CU TLP, XCD-aligned
// replica flush) with ONE change: progressive counted-vmcnt consumption.
// r6 waited vmcnt(0) for the whole 64KB burst before processing element 0;
// here group g is processed under vmcnt(14-2g) while later groups drain.
// Same VGPR/occupancy (unlike r7's failed 2-blocks/CU ILP trade).
__global__ __launch_bounds__(256) void scanK(const float* __restrict__ preds,
                                             const int* __restrict__ targs, int N,
                                             float4* __restrict__ bstat,
                                             unsigned* __restrict__ rep) {
    __shared__ int lh[LHSZ];
    for (int i = threadIdx.x; i < LHSZ; i += 256) lh[i] = 0;
    __syncthreads();

    float pc = 0.f, psig = 0.f, plos = 0.f;
    const int tid = threadIdx.x;
    const int lane = tid & 63;
    const int w = tid >> 6;
    const int dummy = NB2 + lane;            // per-lane dummy slot

    int nfull = N >> 13;                     // full 8192-element tiles
    for (int grp = blockIdx.x; grp < nfull; grp += gridDim.x) {
        size_t ebase = ((size_t)grp << 13) + ((size_t)w << 11) + ((size_t)lane << 2);
        const float* pp  = preds + ebase;        // wave tile: 2048 elements
        const float* pp2 = pp + 1024;
        const int*   tp  = targs + ebase;
        const int*   tp2 = tp + 1024;
        pf4 P[8]; pi4 T[8];
        ISSUE16I(P, T, pp, pp2, tp, tp2);
        WAITG(14); DOGRP(0);
        WAITG(12); DOGRP(1);
        WAITG(10); DOGRP(2);
        WAITG(8);  DOGRP(3);
        WAITG(6);  DOGRP(4);
        WAITG(4);  DOGRP(5);
        WAITG(2);  DOGRP(6);
        WAITG(0);  DOGRP(7);
    }
    // tail elements (N % 8192), last block only
    if (blockIdx.x == gridDim.x - 1) {
        for (int i = (nfull << 13) + tid; i < N; i += 256) {
            float x = preds[i];
            if (targs[i]) { pc += 1.f; psig += sigmoidf_(x); plos += softplusf_(x) - x; }
            else {
                unsigned key = f2key(x);
                if (key >= KEY15) atomicAdd(&lh[(key >> 20) - BUCK0], 1);
            }
        }
    }
    __syncthreads();
    // flush hist (dummy slots >= NB2 ignored); XCD-aligned replica (bid&7).
    // qc dropped: finalize derives qtT = sum(histH) (r8-proven).
    unsigned* my = rep + (unsigned)(blockIdx.x & (NREP - 1)) * NB2;
    for (int i = tid; i < NB2; i += 256) {
        int c = lh[i];
        if (c) atomicAdd(&my[i], (unsigned)c);
    }
#pragma unroll
    for (int o = 32; o > 0; o >>= 1) {
        pc   += __shfl_down(pc, o);
        psig += __shfl_down(psig, o);
        plos += __shfl_down(plos, o);
    }
    __shared__ float rp[4], rs[4], rl[4];
    if ((tid & 63) == 0) { rp[w] = pc; rs[w] = psig; rl[w] = plos; }
    __syncthreads();
    if (tid == 0)
        bstat[blockIdx.x] = make_float4(rp[0] + rp[1] + rp[2] + rp[3],
                                        rs[0] + rs[1] + rs[2] + rs[3],
                                        rl[0] + rl[1] + rl[2] + rl[3], 0.f);
}

// finalizeK (r8-proven): replica reduce -> qtT derived -> stats -> top-k.
__global__ __launch_bounds__(256) void finalizeK(const float* __restrict__ preds,
                                                 const int* __restrict__ targs, int N,
                                                 int nblocks,
                                                 unsigned* __restrict__ ws,
                                                 float* __restrict__ out) {
    __shared__ unsigned histH[NB2];
    __shared__ unsigned sa[256], sb[256];
    __shared__ int sb1;
    __shared__ unsigned sr1;
    __shared__ float rp[4], rs[4], rl[4], rq[4];
    __shared__ double rds[4], rdl[4];
    __shared__ unsigned s_np, s_k, s_flag;
    __shared__ float s_psig, s_plos;

    const float4*   bstat = (const float4*)(ws + BSTAT_OFF);
    const unsigned* rep   = ws + REP_OFF;
    unsigned*       low   = ws + LOW_OFF;
    const int tid = threadIdx.x;
    const int w = tid >> 6;

    // ---- stage B: replica reduce (vectorized) + qtT partial ----
    float qpart = 0.f;
    for (int t = tid; t * 4 < NB2; t += 256) {
        unsigned a0 = 0, a1 = 0, a2 = 0, a3 = 0;
#pragma unroll
        for (int r = 0; r < NREP; r++) {
            uint4 v = *(const uint4*)(rep + r * NB2 + t * 4);
            a0 += v.x; a1 += v.y; a2 += v.z; a3 += v.w;
        }
        histH[t * 4 + 0] = a0; histH[t * 4 + 1] = a1;
        histH[t * 4 + 2] = a2; histH[t * 4 + 3] = a3;
        qpart += (float)a0 + (float)a1 + (float)a2 + (float)a3;
    }

    // ---- stage A: reduce per-block stats + qtT ----
    {
        float pc = 0.f, ps = 0.f, pl = 0.f;
        for (int i = tid; i < nblocks; i += 256) {
            float4 v = bstat[i];
            pc += v.x; ps += v.y; pl += v.z;
        }
#pragma unroll
        for (int o = 32; o > 0; o >>= 1) {
            pc += __shfl_down(pc, o);
            ps += __shfl_down(ps, o);
            pl += __shfl_down(pl, o);
            qpart += __shfl_down(qpart, o);
        }
        if ((tid & 63) == 0) { rp[w] = pc; rs[w] = ps; rl[w] = pl; rq[w] = qpart; }
        __syncthreads();
        if (tid == 0) {
            unsigned np = (unsigned)(rp[0] + rp[1] + rp[2] + rp[3] + 0.5f);
            float psT = rs[0] + rs[1] + rs[2] + rs[3];
            float plT = rl[0] + rl[1] + rl[2] + rl[3];
            unsigned qtT = (unsigned)(rq[0] + rq[1] + rq[2] + rq[3] + 0.5f);
            unsigned nn = (unsigned)N - np;
            unsigned k = (np == 0u) ? (unsigned)(0.1 * (double)nn)
                                    : ((30u * np < nn) ? 30u * np : nn);
            s_np = np; s_psig = psT; s_plos = plT; s_k = k;
            s_flag = (k > qtT) ? 1u : 0u;
        }
    }
    __syncthreads();

    // ---- stage C: fallback low-bucket histogram (pathological only) ----
    if (s_flag) {
        for (int i = tid; i < NBKT; i += 256) low[i] = 0u;   // lazy zero
        __syncthreads();
        for (int i = tid; i < N; i += 256) {
            if (!targs[i]) {
                unsigned key = f2key(preds[i]);
                if (key < KEY15) atomicAdd(&low[key >> 20], 1u);
            }
        }
        __syncthreads();
    }

    // ---- stage D: top-k bucket search + analytic sums ----
    {
        int t = tid;
        int base = t * 16;
        unsigned flag = s_flag;
        unsigned c[16]; unsigned tot = 0;
#pragma unroll
        for (int j = 0; j < 16; j++) {
            int b = base + j;
            unsigned s = (b >= BUCK0) ? histH[b - BUCK0] : (flag ? cload(&low[b]) : 0u);
            c[j] = s; tot += s;
        }
        sa[t] = tot;
        if (t == 0) { sb1 = NBKT; sr1 = 0u; }
        __syncthreads();
        unsigned k = s_k;
        unsigned* src = sa; unsigned* dst = sb;
        for (int off = 1; off < 256; off <<= 1) {
            unsigned v = src[t] + ((t + off < 256) ? src[t + off] : 0u);
            dst[t] = v;
            __syncthreads();
            unsigned* tmp = src; src = dst; dst = tmp;
        }
        if (k > 0u) {
            unsigned above = src[t] - tot;
            if (above < k && above + tot >= k) {
                unsigned cum = above;
                for (int j = 15; j >= 0; j--) {
                    unsigned cc = c[j];
                    if (cum + cc >= k) { sb1 = base + j; sr1 = k - cum; break; }
                    cum += cc;
                }
            }
        }
        __syncthreads();
        int b1 = sb1; unsigned r1 = sr1;
        double ssig = 0.0, ssp = 0.0;
#pragma unroll
        for (int j = 0; j < 16; j++) {
            int b = base + j; unsigned cc = c[j];
            if (cc == 0u) continue;
            bool full = (b > b1);
            bool part = (b == b1) && (r1 > 0u);
            if (!(full || part)) continue;
            float lo = key2f((unsigned)b << 20);
            float hi = (b == NBKT - 1) ? key2f(0xFF7FFFFFu)
                                       : key2f(((unsigned)(b + 1)) << 20);
            if (full) {
                float mid = 0.5f * (lo + hi);
                ssig += (double)cc * (double)sigmoidf_(mid);
                ssp  += (double)cc * (double)softplusf_(mid);
            } else {
                unsigned take = (r1 < cc) ? r1 : cc;
                double q = (double)take / (double)cc;
                float rpv = (float)((double)hi - 0.5 * q * ((double)hi - (double)lo));
                ssig += (double)take * (double)sigmoidf_(rpv);
                ssp  += (double)take * (double)softplusf_(rpv);
            }
        }
#pragma unroll
        for (int o = 32; o > 0; o >>= 1) {
            ssig += __shfl_down(ssig, o);
            ssp  += __shfl_down(ssp, o);
        }
        if ((t & 63) == 0) { rds[w] = ssig; rdl[w] = ssp; }
        __syncthreads();
        if (t == 0) {
            double sns = rds[0] + rds[1] + rds[2] + rds[3];
            double snl = rdl[0] + rdl[1] + rdl[2] + rdl[3];
            unsigned np = s_np;
            float psig2 = s_psig, plos2 = s_plos;
            double denom = (double)psig2 + sns + (double)np;
            double dice = 1.0 - (2.0 * (double)psig2 + (double)EPSF) / (denom + (double)EPSF);
            unsigned totsel = np + s_k;
            double mean = totsel ? (((double)plos2 + snl) / (double)totsel) : 0.0;
            out[0] = (float)(dice + mean);
        }
    }
}

// ---------------------------------------------------------------------------
extern "C" void kernel_launch(void* const* d_in, const int* in_sizes, int n_in,
                              void* d_out, int out_size, void* d_ws, size_t ws_size,
                              hipStream_t stream) {
    const float* preds = (const float*)d_in[0];
    const int*   targs = (const int*)d_in[1];
    float* out = (float*)d_out;
    int N = in_sizes[0];

    unsigned* ws  = (unsigned*)d_ws;
    float4* bstat = (float4*)(ws + BSTAT_OFF);
    unsigned* rep = ws + REP_OFF;

    int nfull = N >> 13;
    int grid = nfull + ((N & 8191) ? 1 : 0);
    if (grid < 1) grid = 1;
    if (grid > 4096) grid = 4096;   // bstat bound; blocks grid-stride past

    zeroAll<<<32, 256, 0, stream>>>(ws);
    scanK<<<grid, 256, 0, stream>>>(preds, targs, N, bstat, rep);
    finalizeK<<<1, 256, 0, stream>>>(preds, targs, N, grid, ws, out);
}